// Round 9
// baseline (115.481 us; speedup 1.0000x reference)
//
#include <hip/hip_runtime.h>
#include <hip/hip_bf16.h>

// NonlocalBlock2D: B=2, C=64, IC=32, H=W=96, N=9216.
// o = Wo @ softmax(theta^T phi) @ g + bo + x  (all 1x1 convs == channel GEMMs)
//
// Round-9: LDS-FREE attention. K/V are 2.36MB total (L2-resident; FETCH
// showed 9.8MB = HBM barely touched), and all MFMA fragment reads are
// coalesced directly from global (K: contiguous 1KB/wave-instr; V: 64B
// chunks, key order pre-permuted at proj time). Deletes LDS staging, both
// per-tile barriers, bank conflicts, and wave lockstep. Epilogue fuses
// combine+out (Op read once, no Y round-trip).

#define B_   2
#define C_   64
#define IC_  32
#define N_   9216
#define QBLK128    72      // N_/128
#define LOG2E 1.44269504088896f

typedef __attribute__((ext_vector_type(4))) float  f32x4;
typedef __attribute__((ext_vector_type(8))) short  s16x8;
typedef __attribute__((ext_vector_type(4))) short  s16x4;

static __device__ __forceinline__ ushort f2bf(float f) {
  union { __hip_bfloat16 h; ushort u; } cv;
  cv.h = __float2bfloat16(f);
  return cv.u;
}

static __device__ __forceinline__ float bf2f(ushort u) {
  union { uint i; float f; } c;
  c.i = ((uint)u) << 16;
  return c.f;
}

static __device__ __forceinline__ f32x4 mfma32(s16x8 a, s16x8 b, f32x4 c) {
  return __builtin_amdgcn_mfma_f32_16x16x32_bf16(a, b, c, 0, 0, 0);
}

// ---------------------------------------------------------------------------
// Kernel 1: projections. theta*log2e->Q[B][N][32], phi->K[B][N][32],
// g->Vt[B][32][N] with keys PERMUTED within each 64-tile:
//   j=n&63, u=j>>5, r=j&31 -> pos = u*32 + (r&15)*2 + (r>>4)
// grid: 4 ic-groups x 72 n-blocks = 288 blocks, 256 thr. Thread: 8 ic, 1 n.
// ---------------------------------------------------------------------------
__global__ __launch_bounds__(256) void proj_kernel(
    const float* __restrict__ x,
    const float* __restrict__ Wg, const float* __restrict__ bg,
    const float* __restrict__ Wt, const float* __restrict__ bt,
    const float* __restrict__ Wp, const float* __restrict__ bp,
    ushort* __restrict__ Qb, ushort* __restrict__ Kb, ushort* __restrict__ Vt)
{
  const int grp = blockIdx.x / 72;          // 0..3 (wave-uniform)
  const int ic0 = grp * 8;
  const int bn  = (blockIdx.x % 72) * 256 + threadIdx.x;
  const int b   = bn / N_;
  const int n   = bn % N_;

  float ag[8], at_[8], ap[8];
#pragma unroll
  for (int j = 0; j < 8; ++j) { ag[j] = 0.f; at_[j] = 0.f; ap[j] = 0.f; }

  const float* xp = x + (size_t)b * C_ * N_ + n;
#pragma unroll 8
  for (int c = 0; c < C_; ++c) {
    const float xv = xp[(size_t)c * N_];
#pragma unroll
    for (int j = 0; j < 8; ++j) {
      ag[j]  = fmaf(Wg[(ic0 + j) * C_ + c], xv, ag[j]);
      at_[j] = fmaf(Wt[(ic0 + j) * C_ + c], xv, at_[j]);
      ap[j]  = fmaf(Wp[(ic0 + j) * C_ + c], xv, ap[j]);
    }
  }

  union { ushort u[8]; s16x8 v; } qv, kv;
#pragma unroll
  for (int j = 0; j < 8; ++j) {
    const int ic = ic0 + j;
    qv.u[j] = f2bf(LOG2E * (at_[j] + bt[ic]));   // theta, exp2 domain
    kv.u[j] = f2bf(ap[j] + bp[ic]);              // phi
  }
  *reinterpret_cast<s16x8*>(Qb + (size_t)bn * IC_ + ic0) = qv.v;
  *reinterpret_cast<s16x8*>(Kb + (size_t)bn * IC_ + ic0) = kv.v;

  // permuted key position for V
  const int j6 = n & 63, u = j6 >> 5, r = j6 & 31;
  const int nperm = (n - j6) + u * 32 + (r & 15) * 2 + (r >> 4);
#pragma unroll
  for (int j = 0; j < 8; ++j) {
    const int ic = ic0 + j;
    Vt[(size_t)(b * IC_ + ic) * N_ + nperm] = f2bf(ag[j] + bg[ic]);
  }
}

// ---------------------------------------------------------------------------
// Kernel 2: flash attention over ONE KV segment, LDS-free.
// block = 4 waves x 32 queries = 128 q; wave holds TWO Q-fragments.
// Fragments loaded straight from global (L2-resident):
//   kf_j  lane(q16,h): Kb[(b*N + key0 + it*64 + j*16 + q16)*32 + h*8]  (1KB coalesced)
//   vf_ud lane(q16,h): Vt[(b*32 + d16*16 + q16)*N + key0 + it*64 + u*32 + h*8]
// No barriers; waves free-run; XCD-swizzled blockIdx for L2 locality.
// p = exp2(S') directly (bounded); denominator via ones-MFMA.
// ---------------------------------------------------------------------------
template<int NSEG>
__global__ __launch_bounds__(256, 4) void attn_kernel(
    const ushort* __restrict__ Qb, const ushort* __restrict__ Kb,
    const ushort* __restrict__ Vt, ushort* __restrict__ Opart,
    float* __restrict__ Lp)
{
  constexpr int NT = 144 / NSEG;           // 64-key tiles per segment
  constexpr int SKEYS = N_ / NSEG;

  // XCD-aware swizzle (grid % 8 == 0): contiguous (b,seg) chunks per XCD
  constexpr int NWG = B_ * NSEG * QBLK128;
  const int bid = blockIdx.x;
  const int wg  = (bid & 7) * (NWG >> 3) + (bid >> 3);

  const int qblk = wg % QBLK128;
  const int bs   = wg / QBLK128;           // b*NSEG + seg
  const int seg  = bs % NSEG;
  const int b    = bs / NSEG;
  const int key0 = seg * SKEYS;

  const int tid  = threadIdx.x;
  const int lane = tid & 63;
  const int wave = tid >> 6;
  const int q16  = lane & 15;
  const int h    = lane >> 4;

  const int qbaseA = qblk * 128 + wave * 32;
  const int qbaseB = qbaseA + 16;

  const short ONE = (short)0x3F80;
  const s16x8 ones = {ONE, ONE, ONE, ONE, ONE, ONE, ONE, ONE};

  const s16x8 qfragA = *reinterpret_cast<const s16x8*>(
      Qb + (size_t)(b * N_ + qbaseA + q16) * IC_ + h * 8);
  const s16x8 qfragB = *reinterpret_cast<const s16x8*>(
      Qb + (size_t)(b * N_ + qbaseB + q16) * IC_ + h * 8);

  f32x4 aA0 = {0.f,0.f,0.f,0.f}, aA1 = {0.f,0.f,0.f,0.f}, aLA = {0.f,0.f,0.f,0.f};
  f32x4 aB0 = {0.f,0.f,0.f,0.f}, aB1 = {0.f,0.f,0.f,0.f}, aLB = {0.f,0.f,0.f,0.f};

  // per-lane global fragment pointers
  const ushort* kp  = Kb + ((size_t)b * N_ + key0 + q16) * IC_ + h * 8;
  const ushort* vp0 = Vt + ((size_t)(b * IC_ + q16)) * N_ + key0 + h * 8;
  const ushort* vp1 = Vt + ((size_t)(b * IC_ + 16 + q16)) * N_ + key0 + h * 8;

  for (int it = 0; it < NT; ++it) {
    // issue all 8 fragment loads (independent; compiler schedules waits)
    const s16x8 kf00 = *reinterpret_cast<const s16x8*>(kp);
    const s16x8 kf01 = *reinterpret_cast<const s16x8*>(kp + 16 * IC_);
    const s16x8 kf10 = *reinterpret_cast<const s16x8*>(kp + 32 * IC_);
    const s16x8 kf11 = *reinterpret_cast<const s16x8*>(kp + 48 * IC_);
    const s16x8 vf00 = *reinterpret_cast<const s16x8*>(vp0);
    const s16x8 vf01 = *reinterpret_cast<const s16x8*>(vp1);
    const s16x8 vf10 = *reinterpret_cast<const s16x8*>(vp0 + 32);
    const s16x8 vf11 = *reinterpret_cast<const s16x8*>(vp1 + 32);
    kp += 64 * IC_; vp0 += 64; vp1 += 64;

    // ---- Phase A: 8 QK^T MFMAs ----
    const f32x4 z = {0.f, 0.f, 0.f, 0.f};
    __builtin_amdgcn_s_setprio(1);
    const f32x4 sA0 = mfma32(kf00, qfragA, z);
    const f32x4 sA1 = mfma32(kf01, qfragA, z);
    const f32x4 sB0 = mfma32(kf00, qfragB, z);
    const f32x4 sB1 = mfma32(kf01, qfragB, z);
    const f32x4 sA2 = mfma32(kf10, qfragA, z);
    const f32x4 sA3 = mfma32(kf11, qfragA, z);
    const f32x4 sB2 = mfma32(kf10, qfragB, z);
    const f32x4 sB3 = mfma32(kf11, qfragB, z);
    __builtin_amdgcn_s_setprio(0);

    // ---- Phase B: exp2 + pack (us[2i]=lo16-group key, us[2i+1]=hi16) ----
    union { ushort us[8]; s16x8 v; } paA0, paA1, paB0, paB1;
#pragma unroll
    for (int i = 0; i < 4; ++i) {
      paA0.us[2 * i]     = f2bf(__builtin_amdgcn_exp2f(sA0[i]));
      paA0.us[2 * i + 1] = f2bf(__builtin_amdgcn_exp2f(sA1[i]));
      paA1.us[2 * i]     = f2bf(__builtin_amdgcn_exp2f(sA2[i]));
      paA1.us[2 * i + 1] = f2bf(__builtin_amdgcn_exp2f(sA3[i]));
      paB0.us[2 * i]     = f2bf(__builtin_amdgcn_exp2f(sB0[i]));
      paB0.us[2 * i + 1] = f2bf(__builtin_amdgcn_exp2f(sB1[i]));
      paB1.us[2 * i]     = f2bf(__builtin_amdgcn_exp2f(sB2[i]));
      paB1.us[2 * i + 1] = f2bf(__builtin_amdgcn_exp2f(sB3[i]));
    }

    // ---- Phase C: 12 PV / denominator MFMAs ----
    __builtin_amdgcn_s_setprio(1);
    aA0 = mfma32(paA0.v, vf00, aA0);
    aA1 = mfma32(paA0.v, vf01, aA1);
    aB0 = mfma32(paB0.v, vf00, aB0);
    aB1 = mfma32(paB0.v, vf01, aB1);
    aA0 = mfma32(paA1.v, vf10, aA0);
    aA1 = mfma32(paA1.v, vf11, aA1);
    aB0 = mfma32(paB1.v, vf10, aB0);
    aB1 = mfma32(paB1.v, vf11, aB1);
    aLA = mfma32(paA0.v, ones, aLA);
    aLA = mfma32(paA1.v, ones, aLA);
    aLB = mfma32(paB0.v, ones, aLB);
    aLB = mfma32(paB1.v, ones, aLB);
    __builtin_amdgcn_s_setprio(0);
  }

  // store partial O (bf16, unnormalized) and partial l (from ones-MFMA)
  const size_t obase0 = ((size_t)(b * NSEG + seg) * N_);
#pragma unroll
  for (int r = 0; r < 4; ++r) {
    const int qA = qbaseA + h * 4 + r;
    const int qB = qbaseB + h * 4 + r;
    Opart[(obase0 + qA) * IC_ + q16]      = f2bf(aA0[r]);
    Opart[(obase0 + qA) * IC_ + 16 + q16] = f2bf(aA1[r]);
    Opart[(obase0 + qB) * IC_ + q16]      = f2bf(aB0[r]);
    Opart[(obase0 + qB) * IC_ + 16 + q16] = f2bf(aB1[r]);
  }
  if (q16 == 0) {
#pragma unroll
    for (int r = 0; r < 4; ++r) {
      Lp[obase0 + qbaseA + h * 4 + r] = aLA[r];
      Lp[obase0 + qbaseB + h * 4 + r] = aLB[r];
    }
  }
}

// ---------------------------------------------------------------------------
// Kernel 3: fused combine + output projection + residual.
// Thread owns one pixel bn: y[32] = sum_s O_s / sum_s l_s (Op read ONCE),
// then o[oc] = Wo[oc]·y + bo[oc] + x for all 64 oc (4 passes of 16).
// grid: B*N/256 = 72 blocks, 256 thr.
// ---------------------------------------------------------------------------
template<int NSEG>
__global__ __launch_bounds__(256) void epilogue_kernel(
    const ushort* __restrict__ Opart, const float* __restrict__ Lp,
    const float* __restrict__ Wo, const float* __restrict__ bo,
    const float* __restrict__ x, float* __restrict__ out)
{
  const int bn = blockIdx.x * 256 + threadIdx.x;
  const int b  = bn / N_;
  const int n  = bn % N_;

  float l = 0.f;
  float y[32];
#pragma unroll
  for (int j = 0; j < 32; ++j) y[j] = 0.f;

  for (int s = 0; s < NSEG; ++s) {
    const size_t base = (size_t)(b * NSEG + s) * N_ + n;
    l += Lp[base];
#pragma unroll
    for (int i = 0; i < 4; ++i) {
      union { s16x8 v; ushort us[8]; } ov;
      ov.v = *reinterpret_cast<const s16x8*>(Opart + base * IC_ + i * 8);
#pragma unroll
      for (int j = 0; j < 8; ++j) y[i * 8 + j] += bf2f(ov.us[j]);
    }
  }
  const float inv = 1.0f / l;
#pragma unroll
  for (int j = 0; j < 32; ++j) y[j] *= inv;

#pragma unroll
  for (int p = 0; p < 4; ++p) {
    float acc[16];
#pragma unroll
    for (int j = 0; j < 16; ++j) acc[j] = bo[p * 16 + j];
#pragma unroll
    for (int ic = 0; ic < IC_; ++ic) {
      const float yv = y[ic];
#pragma unroll
      for (int j = 0; j < 16; ++j)
        acc[j] = fmaf(Wo[(p * 16 + j) * IC_ + ic], yv, acc[j]);
    }
#pragma unroll
    for (int j = 0; j < 16; ++j) {
      const int oc = p * 16 + j;
      const size_t xi = (size_t)(b * C_ + oc) * N_ + n;
      out[xi] = acc[j] + x[xi];
    }
  }
}

// ---------------------------------------------------------------------------
extern "C" void kernel_launch(void* const* d_in, const int* in_sizes, int n_in,
                              void* d_out, int out_size, void* d_ws, size_t ws_size,
                              hipStream_t stream)
{
  const float* x  = (const float*)d_in[0];
  const float* Wg = (const float*)d_in[1];
  const float* bg = (const float*)d_in[2];
  const float* Wt = (const float*)d_in[3];
  const float* bt = (const float*)d_in[4];
  const float* Wp = (const float*)d_in[5];
  const float* bp = (const float*)d_in[6];
  const float* Wo = (const float*)d_in[7];
  const float* bo = (const float*)d_in[8];
  float* out = (float*)d_out;

  char* ws = (char*)d_ws;
  const size_t szb = (size_t)B_ * N_ * IC_ * sizeof(ushort);   // 1,179,648 B
  ushort* Qb = (ushort*)(ws);                       // theta*log2e, bf16 [B][N][32]
  ushort* Kb = (ushort*)(ws + szb);                 // phi, bf16 [B][N][32]
  ushort* Vt = (ushort*)(ws + 2 * szb);             // g,   bf16 [B][32][N] (perm'd)
  ushort* Op = (ushort*)(ws + 3 * szb);             // partial O bf16 [B][S][N][32]

  // choose SEG by available workspace
  const size_t need16 = 3 * szb + 16 * szb + (size_t)16 * B_ * N_ * sizeof(float);

  proj_kernel<<<288, 256, 0, stream>>>(x, Wg, bg, Wt, bt, Wp, bp, Qb, Kb, Vt);
  if (ws_size >= need16) {
    float* Lp = (float*)(ws + 3 * szb + 16 * szb);
    attn_kernel<16><<<B_ * 16 * QBLK128, 256, 0, stream>>>(Qb, Kb, Vt, Op, Lp);
    epilogue_kernel<16><<<(B_ * N_) / 256, 256, 0, stream>>>(Op, Lp, Wo, bo, x, out);
  } else {
    float* Lp = (float*)(ws + 3 * szb + 8 * szb);
    attn_kernel<8><<<B_ * 8 * QBLK128, 256, 0, stream>>>(Qb, Kb, Vt, Op, Lp);
    epilogue_kernel<8><<<(B_ * N_) / 256, 256, 0, stream>>>(Op, Lp, Wo, bo, x, out);
  }
}

// Round 10
// 69.778 us; speedup vs baseline: 1.6550x; 1.6550x over previous
//
#include <hip/hip_runtime.h>
#include <hip/hip_bf16.h>

// NonlocalBlock2D: B=2, C=64, IC=32, H=W=96, N=9216.
// o = Wo @ softmax(theta^T phi) @ g + bo + x  (all 1x1 convs == channel GEMMs)
//
// Round-10: 64 queries/wave (4 Q-fragments) -- each K/V LDS tile read now
// serves 4096 scores (LDS pipe was ~13us of the 43us attn; halves to ~6.5).
// SEG=24 keeps the grid fully resident (1728 blocks, 6.75/CU, no tail).
// Key-halves processed sequentially to keep VGPR under the (256,4) cap of 128
// (r6 lesson: spills are catastrophic). LDS staging kept (r9 lesson: global-
// direct fragment reads put 680MB on the L2 path and lost 23us).

#define B_   2
#define C_   64
#define IC_  32
#define N_   9216
#define LOG2E 1.44269504088896f

typedef __attribute__((ext_vector_type(4))) float  f32x4;
typedef __attribute__((ext_vector_type(8))) short  s16x8;
typedef __attribute__((ext_vector_type(4))) short  s16x4;

static __device__ __forceinline__ ushort f2bf(float f) {
  union { __hip_bfloat16 h; ushort u; } cv;
  cv.h = __float2bfloat16(f);
  return cv.u;
}

static __device__ __forceinline__ float bf2f(ushort u) {
  union { uint i; float f; } c;
  c.i = ((uint)u) << 16;
  return c.f;
}

static __device__ __forceinline__ f32x4 mfma32(s16x8 a, s16x8 b, f32x4 c) {
  return __builtin_amdgcn_mfma_f32_16x16x32_bf16(a, b, c, 0, 0, 0);
}

// ---------------------------------------------------------------------------
// Kernel 1: projections. theta*log2e->Q[B][N][32], phi->K[B][N][32],
// g->Vt[B][32][N] with keys PERMUTED within each 64-tile:
//   j=n&63, u=j>>5, r=j&31 -> pos = u*32 + (r&15)*2 + (r>>4)
// grid: 4 ic-groups x 72 n-blocks = 288 blocks, 256 thr. Thread: 8 ic, 1 n.
// ---------------------------------------------------------------------------
__global__ __launch_bounds__(256) void proj_kernel(
    const float* __restrict__ x,
    const float* __restrict__ Wg, const float* __restrict__ bg,
    const float* __restrict__ Wt, const float* __restrict__ bt,
    const float* __restrict__ Wp, const float* __restrict__ bp,
    ushort* __restrict__ Qb, ushort* __restrict__ Kb, ushort* __restrict__ Vt)
{
  const int grp = blockIdx.x / 72;          // 0..3 (wave-uniform)
  const int ic0 = grp * 8;
  const int bn  = (blockIdx.x % 72) * 256 + threadIdx.x;
  const int b   = bn / N_;
  const int n   = bn % N_;

  float ag[8], at_[8], ap[8];
#pragma unroll
  for (int j = 0; j < 8; ++j) { ag[j] = 0.f; at_[j] = 0.f; ap[j] = 0.f; }

  const float* xp = x + (size_t)b * C_ * N_ + n;
#pragma unroll 8
  for (int c = 0; c < C_; ++c) {
    const float xv = xp[(size_t)c * N_];
#pragma unroll
    for (int j = 0; j < 8; ++j) {
      ag[j]  = fmaf(Wg[(ic0 + j) * C_ + c], xv, ag[j]);
      at_[j] = fmaf(Wt[(ic0 + j) * C_ + c], xv, at_[j]);
      ap[j]  = fmaf(Wp[(ic0 + j) * C_ + c], xv, ap[j]);
    }
  }

  union { ushort u[8]; s16x8 v; } qv, kv;
#pragma unroll
  for (int j = 0; j < 8; ++j) {
    const int ic = ic0 + j;
    qv.u[j] = f2bf(LOG2E * (at_[j] + bt[ic]));   // theta, exp2 domain
    kv.u[j] = f2bf(ap[j] + bp[ic]);              // phi
  }
  *reinterpret_cast<s16x8*>(Qb + (size_t)bn * IC_ + ic0) = qv.v;
  *reinterpret_cast<s16x8*>(Kb + (size_t)bn * IC_ + ic0) = kv.v;

  // permuted key position for V
  const int j6 = n & 63, u = j6 >> 5, r = j6 & 31;
  const int nperm = (n - j6) + u * 32 + (r & 15) * 2 + (r >> 4);
#pragma unroll
  for (int j = 0; j < 8; ++j) {
    const int ic = ic0 + j;
    Vt[(size_t)(b * IC_ + ic) * N_ + nperm] = f2bf(ag[j] + bg[ic]);
  }
}

// ---------------------------------------------------------------------------
// Kernel 2: flash attention over ONE KV segment (N_/NSEG keys, tiles of 64).
// block = 4 waves x 64 queries = 256 q; wave holds FOUR Q-fragments so each
// K/V LDS tile read serves 4096 scores. Swapped QK^T: mfma(K,Q).
// p = exp2(S') directly (bounded; partials merge by summation).
// Key-halves (u=0,1) processed sequentially to bound register pressure.
// Denominator via ones-MFMA. LDS single-buffered, 2 barriers/tile.
// ---------------------------------------------------------------------------
template<int NSEG>
__global__ __launch_bounds__(256, 4) void attn_kernel(
    const ushort* __restrict__ Qb, const ushort* __restrict__ Kb,
    const ushort* __restrict__ Vt, ushort* __restrict__ Opart,
    float* __restrict__ Lp)
{
  constexpr int NT = 144 / NSEG;           // 64-key tiles per segment
  constexpr int SKEYS = N_ / NSEG;
  constexpr int QBLK = N_ / 256;           // 36 q-blocks
  constexpr int KSTR = 36;                 // 72B rows
  constexpr int VSTR = 70;                 // 140B rows
  __shared__ __align__(16) ushort Kl[64 * KSTR];
  __shared__ __align__(16) ushort Vl[32 * VSTR];

  const int qblk = blockIdx.x % QBLK;
  const int bs   = blockIdx.x / QBLK;      // b*NSEG + seg
  const int seg  = bs % NSEG;
  const int b    = bs / NSEG;
  const int key0 = seg * SKEYS;

  const int tid  = threadIdx.x;
  const int lane = tid & 63;
  const int wave = tid >> 6;
  const int q16  = lane & 15;
  const int h    = lane >> 4;

  const int qbase = qblk * 256 + wave * 64;   // 4 frags: qbase + 16f

  const short ONE = (short)0x3F80;
  const s16x8 ones = {ONE, ONE, ONE, ONE, ONE, ONE, ONE, ONE};

  const ushort* qptr = Qb + (size_t)(b * N_ + qbase + q16) * IC_ + h * 8;
  const s16x8 qfA = *reinterpret_cast<const s16x8*>(qptr);
  const s16x8 qfB = *reinterpret_cast<const s16x8*>(qptr + 16 * IC_);
  const s16x8 qfC = *reinterpret_cast<const s16x8*>(qptr + 32 * IC_);
  const s16x8 qfD = *reinterpret_cast<const s16x8*>(qptr + 48 * IC_);

  f32x4 aA0 = {0.f,0.f,0.f,0.f}, aA1 = {0.f,0.f,0.f,0.f}, aLA = {0.f,0.f,0.f,0.f};
  f32x4 aB0 = {0.f,0.f,0.f,0.f}, aB1 = {0.f,0.f,0.f,0.f}, aLB = {0.f,0.f,0.f,0.f};
  f32x4 aC0 = {0.f,0.f,0.f,0.f}, aC1 = {0.f,0.f,0.f,0.f}, aLC = {0.f,0.f,0.f,0.f};
  f32x4 aD0 = {0.f,0.f,0.f,0.f}, aD1 = {0.f,0.f,0.f,0.f}, aLD = {0.f,0.f,0.f,0.f};

  // staging: K tile 4KB + V tile 4KB; 256 threads x 16B each.
  const int krow = tid >> 2, kpart = tid & 3;
  const ushort* kg = Kb + ((size_t)b * N_ + key0 + krow) * IC_ + kpart * 8;
  ushort* kl_dst = &Kl[krow * KSTR + kpart * 8];

  const int vd = tid >> 3, vpp = tid & 7;
  const ushort* vg = Vt + (size_t)(b * IC_ + vd) * N_ + key0 + vpp * 8;
  ushort* vl_dst = &Vl[vd * VSTR + vpp * 8];

  s16x8 kreg = *reinterpret_cast<const s16x8*>(kg);
  s16x8 vreg = *reinterpret_cast<const s16x8*>(vg);

  for (int it = 0; it < NT; ++it) {
    *reinterpret_cast<s16x8*>(kl_dst) = kreg;
    *reinterpret_cast<s16x8*>(vl_dst) = vreg;
    __syncthreads();

    if (it + 1 < NT) {
      kg += 64 * IC_;
      vg += 64;
      kreg = *reinterpret_cast<const s16x8*>(kg);
      vreg = *reinterpret_cast<const s16x8*>(vg);
    }

    // two key-halves sequentially (bounds VGPR: one kf/vf pair set live)
#pragma unroll
    for (int u = 0; u < 2; ++u) {
      const s16x8 kf0 = *reinterpret_cast<const s16x8*>(&Kl[(u * 32 + q16) * KSTR + h * 8]);
      const s16x8 kf1 = *reinterpret_cast<const s16x8*>(&Kl[(u * 32 + 16 + q16) * KSTR + h * 8]);
      const s16x8 vf0 = *reinterpret_cast<const s16x8*>(&Vl[q16 * VSTR + u * 32 + h * 8]);
      const s16x8 vf1 = *reinterpret_cast<const s16x8*>(&Vl[(16 + q16) * VSTR + u * 32 + h * 8]);
      const f32x4 z = {0.f, 0.f, 0.f, 0.f};

      // ---- qfrag A ----
      {
        __builtin_amdgcn_s_setprio(1);
        const f32x4 s0 = mfma32(kf0, qfA, z);
        const f32x4 s1 = mfma32(kf1, qfA, z);
        __builtin_amdgcn_s_setprio(0);
        union { ushort us[8]; s16x8 v; } pa;
#pragma unroll
        for (int i = 0; i < 4; ++i) {
          pa.us[2 * i]     = f2bf(__builtin_amdgcn_exp2f(s0[i]));
          pa.us[2 * i + 1] = f2bf(__builtin_amdgcn_exp2f(s1[i]));
        }
        __builtin_amdgcn_s_setprio(1);
        aA0 = mfma32(pa.v, vf0, aA0);
        aA1 = mfma32(pa.v, vf1, aA1);
        aLA = mfma32(pa.v, ones, aLA);
        __builtin_amdgcn_s_setprio(0);
      }
      // ---- qfrag B ----
      {
        __builtin_amdgcn_s_setprio(1);
        const f32x4 s0 = mfma32(kf0, qfB, z);
        const f32x4 s1 = mfma32(kf1, qfB, z);
        __builtin_amdgcn_s_setprio(0);
        union { ushort us[8]; s16x8 v; } pa;
#pragma unroll
        for (int i = 0; i < 4; ++i) {
          pa.us[2 * i]     = f2bf(__builtin_amdgcn_exp2f(s0[i]));
          pa.us[2 * i + 1] = f2bf(__builtin_amdgcn_exp2f(s1[i]));
        }
        __builtin_amdgcn_s_setprio(1);
        aB0 = mfma32(pa.v, vf0, aB0);
        aB1 = mfma32(pa.v, vf1, aB1);
        aLB = mfma32(pa.v, ones, aLB);
        __builtin_amdgcn_s_setprio(0);
      }
      // ---- qfrag C ----
      {
        __builtin_amdgcn_s_setprio(1);
        const f32x4 s0 = mfma32(kf0, qfC, z);
        const f32x4 s1 = mfma32(kf1, qfC, z);
        __builtin_amdgcn_s_setprio(0);
        union { ushort us[8]; s16x8 v; } pa;
#pragma unroll
        for (int i = 0; i < 4; ++i) {
          pa.us[2 * i]     = f2bf(__builtin_amdgcn_exp2f(s0[i]));
          pa.us[2 * i + 1] = f2bf(__builtin_amdgcn_exp2f(s1[i]));
        }
        __builtin_amdgcn_s_setprio(1);
        aC0 = mfma32(pa.v, vf0, aC0);
        aC1 = mfma32(pa.v, vf1, aC1);
        aLC = mfma32(pa.v, ones, aLC);
        __builtin_amdgcn_s_setprio(0);
      }
      // ---- qfrag D ----
      {
        __builtin_amdgcn_s_setprio(1);
        const f32x4 s0 = mfma32(kf0, qfD, z);
        const f32x4 s1 = mfma32(kf1, qfD, z);
        __builtin_amdgcn_s_setprio(0);
        union { ushort us[8]; s16x8 v; } pa;
#pragma unroll
        for (int i = 0; i < 4; ++i) {
          pa.us[2 * i]     = f2bf(__builtin_amdgcn_exp2f(s0[i]));
          pa.us[2 * i + 1] = f2bf(__builtin_amdgcn_exp2f(s1[i]));
        }
        __builtin_amdgcn_s_setprio(1);
        aD0 = mfma32(pa.v, vf0, aD0);
        aD1 = mfma32(pa.v, vf1, aD1);
        aLD = mfma32(pa.v, ones, aLD);
        __builtin_amdgcn_s_setprio(0);
      }
    }
    __syncthreads();
  }

  // store partial O (bf16, unnormalized) and partial l (from ones-MFMA)
  const size_t obase0 = ((size_t)(b * NSEG + seg) * N_);
#pragma unroll
  for (int r = 0; r < 4; ++r) {
    const int qA = qbase + h * 4 + r;
    Opart[(obase0 + qA) * IC_ + q16]           = f2bf(aA0[r]);
    Opart[(obase0 + qA) * IC_ + 16 + q16]      = f2bf(aA1[r]);
    Opart[(obase0 + qA + 16) * IC_ + q16]      = f2bf(aB0[r]);
    Opart[(obase0 + qA + 16) * IC_ + 16 + q16] = f2bf(aB1[r]);
    Opart[(obase0 + qA + 32) * IC_ + q16]      = f2bf(aC0[r]);
    Opart[(obase0 + qA + 32) * IC_ + 16 + q16] = f2bf(aC1[r]);
    Opart[(obase0 + qA + 48) * IC_ + q16]      = f2bf(aD0[r]);
    Opart[(obase0 + qA + 48) * IC_ + 16 + q16] = f2bf(aD1[r]);
  }
  if (q16 == 0) {
#pragma unroll
    for (int r = 0; r < 4; ++r) {
      Lp[obase0 + qbase + h * 4 + r]      = aLA[r];
      Lp[obase0 + qbase + 16 + h * 4 + r] = aLB[r];
      Lp[obase0 + qbase + 32 + h * 4 + r] = aLC[r];
      Lp[obase0 + qbase + 48 + h * 4 + r] = aLD[r];
    }
  }
}

// ---------------------------------------------------------------------------
// Kernel 2b: combine partials -> Y (bf16). y[bn][d] = sum_s O_s / sum_s l_s.
// 8 threads per bn (4 dims each). grid 576 x 256.
// ---------------------------------------------------------------------------
template<int NSEG>
__global__ __launch_bounds__(256) void combine_kernel(
    const ushort* __restrict__ Opart, const float* __restrict__ Lp,
    ushort* __restrict__ Y)
{
  const int idx = blockIdx.x * 256 + threadIdx.x;
  const int bn  = idx >> 3;
  const int e   = idx & 7;        // 4-dim eighth
  const int b   = bn / N_;
  const int q   = bn % N_;

  float l = 0.f;
  float o[4];
#pragma unroll
  for (int j = 0; j < 4; ++j) o[j] = 0.f;

#pragma unroll
  for (int s = 0; s < NSEG; ++s) {
    const size_t base = (size_t)(b * NSEG + s) * N_ + q;
    l += Lp[base];
    union { s16x4 v; ushort us[4]; } ov;
    ov.v = *reinterpret_cast<const s16x4*>(Opart + base * IC_ + e * 4);
#pragma unroll
    for (int j = 0; j < 4; ++j) o[j] += bf2f(ov.us[j]);
  }
  const float inv = 1.0f / l;
  union { ushort us[4]; s16x4 v; } yv;
#pragma unroll
  for (int j = 0; j < 4; ++j) yv.us[j] = f2bf(o[j] * inv);
  *reinterpret_cast<s16x4*>(Y + (size_t)bn * IC_ + e * 4) = yv.v;
}

// ---------------------------------------------------------------------------
// Kernel 3: o = Wo @ y + bo + x. grid: 16 oc-groups x 72 n-blocks = 1152.
// Thread: 4 oc, 1 bn. Y is bf16 (1.2MB, L2-resident -> re-reads cheap).
// ---------------------------------------------------------------------------
__global__ __launch_bounds__(256) void out_kernel(
    const ushort* __restrict__ Y, const float* __restrict__ Wo,
    const float* __restrict__ bo, const float* __restrict__ x,
    float* __restrict__ out)
{
  const int g    = blockIdx.x / 72;   // oc group 0..15 (wave-uniform), 4 oc each
  const int oc0  = g * 4;
  const int bn   = (blockIdx.x % 72) * 256 + threadIdx.x;
  const int b    = bn / N_;
  const int n    = bn % N_;

  float yv[32];
#pragma unroll
  for (int i = 0; i < 4; ++i) {
    union { s16x8 v; ushort us[8]; } ov;
    ov.v = *reinterpret_cast<const s16x8*>(Y + (size_t)bn * IC_ + i * 8);
#pragma unroll
    for (int j = 0; j < 8; ++j) yv[i * 8 + j] = bf2f(ov.us[j]);
  }

  float acc[4];
#pragma unroll
  for (int j = 0; j < 4; ++j) acc[j] = bo[oc0 + j];

#pragma unroll
  for (int ic = 0; ic < IC_; ++ic) {
    const float yv_ic = yv[ic];
#pragma unroll
    for (int j = 0; j < 4; ++j)
      acc[j] = fmaf(Wo[(oc0 + j) * IC_ + ic], yv_ic, acc[j]);
  }

#pragma unroll
  for (int j = 0; j < 4; ++j) {
    const int oc = oc0 + j;
    const size_t xi = (size_t)(b * C_ + oc) * N_ + n;
    out[xi] = acc[j] + x[xi];
  }
}

// ---------------------------------------------------------------------------
extern "C" void kernel_launch(void* const* d_in, const int* in_sizes, int n_in,
                              void* d_out, int out_size, void* d_ws, size_t ws_size,
                              hipStream_t stream)
{
  const float* x  = (const float*)d_in[0];
  const float* Wg = (const float*)d_in[1];
  const float* bg = (const float*)d_in[2];
  const float* Wt = (const float*)d_in[3];
  const float* bt = (const float*)d_in[4];
  const float* Wp = (const float*)d_in[5];
  const float* bp = (const float*)d_in[6];
  const float* Wo = (const float*)d_in[7];
  const float* bo = (const float*)d_in[8];
  float* out = (float*)d_out;

  char* ws = (char*)d_ws;
  const size_t szb = (size_t)B_ * N_ * IC_ * sizeof(ushort);   // 1,179,648 B
  ushort* Qb = (ushort*)(ws);                       // theta*log2e, bf16 [B][N][32]
  ushort* Kb = (ushort*)(ws + szb);                 // phi, bf16 [B][N][32]
  ushort* Vt = (ushort*)(ws + 2 * szb);             // g,   bf16 [B][32][N] (perm'd)
  ushort* Op = (ushort*)(ws + 3 * szb);             // partial O bf16 [B][S][N][32]
  // Y (bf16, 1.18 MB) aliases Qb: combine runs after attn finished reading Q.
  ushort* Yb = (ushort*)(ws);

  const size_t need24 = 3 * szb + 24 * szb + (size_t)24 * B_ * N_ * sizeof(float);
  const size_t need16 = 3 * szb + 16 * szb + (size_t)16 * B_ * N_ * sizeof(float);

  proj_kernel<<<288, 256, 0, stream>>>(x, Wg, bg, Wt, bt, Wp, bp, Qb, Kb, Vt);
  if (ws_size >= need24) {
    float* Lp = (float*)(ws + 3 * szb + 24 * szb);
    attn_kernel<24><<<B_ * 24 * (N_ / 256), 256, 0, stream>>>(Qb, Kb, Vt, Op, Lp);
    combine_kernel<24><<<(B_ * N_ * 8) / 256, 256, 0, stream>>>(Op, Lp, Yb);
  } else if (ws_size >= need16) {
    float* Lp = (float*)(ws + 3 * szb + 16 * szb);
    attn_kernel<16><<<B_ * 16 * (N_ / 256), 256, 0, stream>>>(Qb, Kb, Vt, Op, Lp);
    combine_kernel<16><<<(B_ * N_ * 8) / 256, 256, 0, stream>>>(Op, Lp, Yb);
  } else {
    float* Lp = (float*)(ws + 3 * szb + 8 * szb);
    attn_kernel<8><<<B_ * 8 * (N_ / 256), 256, 0, stream>>>(Qb, Kb, Vt, Op, Lp);
    combine_kernel<8><<<(B_ * N_ * 8) / 256, 256, 0, stream>>>(Op, Lp, Yb);
  }
  out_kernel<<<16 * 72, 256, 0, stream>>>(Yb, Wo, bo, x, out);
}